// Round 8
// baseline (253.922 us; speedup 1.0000x reference)
//
#include <hip/hip_runtime.h>
#include <hip/hip_bf16.h>

#define NN 100000
#define NE 3200000
#define NF 512
#define NH 16
#define NC 16
#define EPSF 1e-12f

// Bucketed edge staging: bucket = 256 consecutive dst nodes.
#define BNODES 256
#define NBUK ((NN + BNODES - 1) / BNODES)   // 391
#define BIN_BLOCKS 256
#define BIN_T 1024
#define BCAP 32                              // per-bucket LDS line buffer (u32)
#define BSLACK (BIN_BLOCKS * 16 + 16)        // per-bucket staging slack (sentinel lines)
#define SENT 0xFFFFFFFFu
#define SCAP 9216                            // sorted-edge cap per bucket (mean 8184+256 pad, +8 sigma)

typedef unsigned short u16;

__device__ __forceinline__ float bf2f(u16 v) {
  return __uint_as_float(((unsigned int)v) << 16);
}
__device__ __forceinline__ u16 f2bf(float f) {
  unsigned int u = __float_as_uint(f);
  u += 0x7fffu + ((u >> 16) & 1u);   // round-to-nearest-even
  return (u16)(u >> 16);
}
// unpack 8 bf16 (one uint4) to f32
__device__ __forceinline__ void unpack8(uint4 q, float* f) {
  f[0] = __uint_as_float(q.x << 16); f[1] = __uint_as_float(q.x & 0xffff0000u);
  f[2] = __uint_as_float(q.y << 16); f[3] = __uint_as_float(q.y & 0xffff0000u);
  f[4] = __uint_as_float(q.z << 16); f[5] = __uint_as_float(q.z & 0xffff0000u);
  f[6] = __uint_as_float(q.w << 16); f[7] = __uint_as_float(q.w & 0xffff0000u);
}

// ---------------- Kernel A: h1 = relu(x@W1 + b1), rnorm1; also zero bcnt ----
__global__ __launch_bounds__(256) void k_feat(const float* __restrict__ x,
    const float* __restrict__ W1, const float* __restrict__ b1,
    u16* __restrict__ h, float* __restrict__ rn, int* __restrict__ bcnt) {
  const int tid = threadIdx.x;
  for (int g = blockIdx.x * 256 + tid; g < NBUK; g += gridDim.x * 256)
    bcnt[g] = 0;

  __shared__ float part[4][64][20];

  const int lane = tid & 63;
  const int q = __builtin_amdgcn_readfirstlane(tid >> 6);  // wave-uniform K-quarter
  const int base = blockIdx.x * 64;
  int row = base + lane;
  if (row >= NN) row = NN - 1;

  const float* wq = W1 + q * 128 * NH;                     // uniform -> s_load
  const float4* xp = (const float4*)(x + (size_t)row * NF + q * 128);

  float acc[16];
  #pragma unroll
  for (int j = 0; j < 16; ++j) acc[j] = 0.f;

  #pragma unroll 2
  for (int kk = 0; kk < 32; ++kk) {
    const float4 xv = xp[kk];
    #pragma unroll
    for (int dk = 0; dk < 4; ++dk) {
      const float* wrow = wq + (kk * 4 + dk) * NH;
      const float xs = (dk == 0) ? xv.x : (dk == 1) ? xv.y : (dk == 2) ? xv.z : xv.w;
      #pragma unroll
      for (int j = 0; j < 16; ++j)
        acc[j] = fmaf(xs, wrow[j], acc[j]);
    }
  }

  #pragma unroll
  for (int j4 = 0; j4 < 4; ++j4)
    *(float4*)&part[q][lane][j4 * 4] =
        make_float4(acc[j4 * 4], acc[j4 * 4 + 1], acc[j4 * 4 + 2], acc[j4 * 4 + 3]);
  __syncthreads();

  const int r2 = tid >> 2;
  const int jg = (tid & 3) * 4;
  const int orow = base + r2;
  float o[4];
  #pragma unroll
  for (int jj = 0; jj < 4; ++jj) {
    const int j = jg + jj;
    float s = part[0][r2][j] + part[1][r2][j] + part[2][r2][j] + part[3][r2][j];
    o[jj] = fmaxf(s + b1[j], 0.f);
  }
  float ss = o[0] * o[0] + o[1] * o[1] + o[2] * o[2] + o[3] * o[3];
  ss += __shfl_xor(ss, 1, 64);
  ss += __shfl_xor(ss, 2, 64);
  const float rv = 1.0f / fmaxf(sqrtf(ss), EPSF);
  if (orow < NN) {
    ushort4 hv;
    hv.x = f2bf(o[0]); hv.y = f2bf(o[1]); hv.z = f2bf(o[2]); hv.w = f2bf(o[3]);
    *(ushort4*)(h + (size_t)orow * NH + jg) = hv;
    if ((tid & 3) == 0) rn[orow] = rv;
  }
}

// ---------------- bucket counts (LDS-aggregated) ----------------
__global__ __launch_bounds__(256) void k_bcount(const int* __restrict__ dst,
                                                int* __restrict__ bcnt) {
  __shared__ int l[NBUK];
  for (int i = threadIdx.x; i < NBUK; i += 256) l[i] = 0;
  __syncthreads();
  const int stride = gridDim.x * 256;
  for (int e = blockIdx.x * 256 + threadIdx.x; e < NE; e += stride)
    atomicAdd(&l[dst[e] >> 8], 1);
  __syncthreads();
  for (int i = threadIdx.x; i < NBUK; i += 256)
    if (l[i]) atomicAdd(&bcnt[i], l[i]);
}

// ---------------- bucket region scan (16-aligned, slack for sentinel lines) --
__global__ void k_bscan(const int* __restrict__ bcnt, int* __restrict__ bbase,
                        int* __restrict__ bcur) {
  __shared__ int sm[512];
  const int tid = threadIdx.x;
  int cap = 0;
  if (tid < NBUK) cap = ((bcnt[tid] + 15) & ~15) + BSLACK;
  sm[tid] = cap;
  __syncthreads();
  for (int s = 1; s < 512; s <<= 1) {
    int t = (tid >= s) ? sm[tid - s] : 0;
    __syncthreads();
    sm[tid] += t;
    __syncthreads();
  }
  if (tid < NBUK) { const int ex = sm[tid] - cap; bbase[tid] = ex; bcur[tid] = ex; }
}

// ---------------- binning: full-line (64B aligned) staging writes only -------
// stg entry = (src << 8) | (dst & 255); SENT = padding, skipped downstream.
__global__ __launch_bounds__(BIN_T) void k_bin(const int* __restrict__ srcs,
    const int* __restrict__ dsts, int* __restrict__ bcur,
    unsigned* __restrict__ stg) {
  __shared__ unsigned buf[NBUK][BCAP];
  __shared__ int cnt[NBUK];
  const int tid = threadIdx.x;
  for (int i = tid; i < NBUK; i += BIN_T) cnt[i] = 0;
  __syncthreads();
  const int perblk = (NE + BIN_BLOCKS - 1) / BIN_BLOCKS;   // 12500
  const int e0 = blockIdx.x * perblk;
  const int e1 = (e0 + perblk < NE) ? e0 + perblk : NE;
  for (int base = e0; base < e1; base += BIN_T) {
    const int e = base + tid;
    if (e < e1) {
      const int d = dsts[e];
      const unsigned pv = ((unsigned)srcs[e] << 8) | (unsigned)(d & (BNODES - 1));
      const int b = d >> 8;
      const int slot = atomicAdd(&cnt[b], 1);
      if (slot < BCAP) {
        buf[b][slot] = pv;
      } else {                    // ~never: direct aligned-line write
        const int g = atomicAdd(&bcur[b], 16);
        stg[g] = pv;
        for (int t = 1; t < 16; ++t) stg[g + t] = SENT;
        atomicSub(&cnt[b], 1);
      }
    }
    __syncthreads();
    for (int b = tid; b < NBUK; b += BIN_T) {   // flush full 64B lines from top
      int c = cnt[b];
      while (c >= 16) {
        const int g = atomicAdd(&bcur[b], 16);
        #pragma unroll
        for (int t = 0; t < 16; t += 4)
          *(uint4*)&stg[g + t] = make_uint4(buf[b][c - 16 + t], buf[b][c - 15 + t],
                                            buf[b][c - 14 + t], buf[b][c - 13 + t]);
        c -= 16;
      }
      cnt[b] = c;
    }
    __syncthreads();
  }
  for (int b = tid; b < NBUK; b += BIN_T) {      // tail: sentinel-pad to a line
    const int c = cnt[b];
    if (c > 0) {
      for (int t = c; t < 16; ++t) buf[b][t] = SENT;
      const int g = atomicAdd(&bcur[b], 16);
      #pragma unroll
      for (int t = 0; t < 16; t += 4)
        *(uint4*)&stg[g + t] = make_uint4(buf[b][t], buf[b][t + 1],
                                          buf[b][t + 2], buf[b][t + 3]);
    }
  }
}

// ---------------- one-time sort: stg -> per-node-grouped global CSR ----------
// Block = bucket. LDS counting-sort (count/scan/scatter, +1-slot pad per node),
// then COALESCED flush of the sorted list to csrg[b*SCAP..] (full clean lines)
// and coalesced per-node nbase/ndeg writes. Done ONCE, used by both props.
__global__ __launch_bounds__(1024) void k_sort(const unsigned* __restrict__ stg,
    const int* __restrict__ bbase, const int* __restrict__ bcur,
    unsigned* __restrict__ csrg, int* __restrict__ nbase, int* __restrict__ ndeg) {
  __shared__ unsigned srt[SCAP];        // 36 KB
  __shared__ int sm[BNODES];
  __shared__ int lbase[BNODES];
  __shared__ int lcur[BNODES];

  const int tid = threadIdx.x;
  const int b = blockIdx.x;
  const int n0 = b * BNODES;
  const int nloc = (NN - n0 < BNODES) ? NN - n0 : BNODES;
  const int s0 = bbase[b];
  const int ecnt = bcur[b] - s0;
  const int gb = b * SCAP;

  if (tid < BNODES) sm[tid] = 0;
  __syncthreads();

  for (int i = tid; i < ecnt; i += 1024) {           // count
    const unsigned v = stg[s0 + i];
    if (v != SENT) atomicAdd(&sm[v & (BNODES - 1)], 1);
  }
  __syncthreads();

  int myc = 0;                                        // scan of (cnt+1)
  if (tid < BNODES) { myc = sm[tid]; sm[tid] = myc + 1; }
  __syncthreads();
  for (int s = 1; s < BNODES; s <<= 1) {
    int t = (tid < BNODES && tid >= s) ? sm[tid - s] : 0;
    __syncthreads();
    if (tid < BNODES) sm[tid] += t;
    __syncthreads();
  }
  if (tid < BNODES) {
    const int ex = sm[tid] - (myc + 1);
    lbase[tid] = ex;
    lcur[tid] = ex;
  }
  __syncthreads();

  for (int i = tid; i < ecnt; i += 1024) {           // scatter-sort into LDS
    const unsigned v = stg[s0 + i];
    if (v != SENT) {
      const int slot = atomicAdd(&lcur[v & (BNODES - 1)], 1);
      if (slot < SCAP) srt[slot] = v >> 8;
    }
  }
  __syncthreads();

  int tot = sm[BNODES - 1];                           // incl. padded total
  if (tot > SCAP) tot = SCAP;
  for (int i = tid; i < tot; i += 1024)               // coalesced full-line flush
    csrg[gb + i] = srt[i];
  if (tid < nloc) {
    nbase[n0 + tid] = gb + lbase[tid];
    ndeg[n0 + tid] = (tid < BNODES) ? (lcur[tid] - lbase[tid]) : 0;
  }
}

// ---------------- Prop: pure gather-compute, 4 threads/node, no LDS ----------
// Each quad-thread: full 16-dim dot in registers per edge (2x uint4 gather of
// L2-resident h row), one __expf, register accumulate; quad DPP combine.
// Softmax shift skipped (logits bounded by |beta|); +1 virtual self-loop.
template <bool FINAL>
__global__ __launch_bounds__(256) void k_prop(const u16* __restrict__ hp,
    const float* __restrict__ rnp, const unsigned* __restrict__ csrg,
    const int* __restrict__ nbase, const int* __restrict__ ndeg,
    const float* __restrict__ betap,
    u16* __restrict__ ho, float* __restrict__ rno,
    const float* __restrict__ W2, const float* __restrict__ b2,
    float* __restrict__ out) {
  const int t = blockIdx.x * 256 + threadIdx.x;
  const int es = t & 3;
  const int n = t >> 2;
  if (n >= NN) return;
  const float beta = betap ? betap[0] : 1.0f;

  const uint4 d0 = *(const uint4*)(hp + (size_t)n * NH);
  const uint4 d1 = *(const uint4*)(hp + (size_t)n * NH + 8);
  float hd[16];
  unpack8(d0, hd); unpack8(d1, hd + 8);
  const float rv = rnp[n];
  const float brd = beta * rv;
  const int off = nbase[n];
  const int deg = ndeg[n];

  float acc[16];
  #pragma unroll
  for (int k = 0; k < 16; ++k) acc[k] = 0.f;
  float ssum = 0.f;

  for (int i = es; i < deg + 1; i += 4) {             // +1 virtual self-loop
    float hs[16], rns;
    if (i < deg) {
      const int src = (int)csrg[off + i];
      const uint4 q0 = *(const uint4*)(hp + (size_t)src * NH);
      const uint4 q1 = *(const uint4*)(hp + (size_t)src * NH + 8);
      unpack8(q0, hs); unpack8(q1, hs + 8);
      rns = rnp[src];
    } else {
      #pragma unroll
      for (int k = 0; k < 16; ++k) hs[k] = hd[k];
      rns = rv;
    }
    float p0 = 0.f, p1 = 0.f, p2 = 0.f, p3 = 0.f;
    #pragma unroll
    for (int k = 0; k < 4; ++k) {
      p0 = fmaf(hs[k],      hd[k],      p0);
      p1 = fmaf(hs[k + 4],  hd[k + 4],  p1);
      p2 = fmaf(hs[k + 8],  hd[k + 8],  p2);
      p3 = fmaf(hs[k + 12], hd[k + 12], p3);
    }
    const float p = (p0 + p1) + (p2 + p3);
    const float w = __expf(brd * rns * p);
    #pragma unroll
    for (int k = 0; k < 16; ++k) acc[k] = fmaf(w, hs[k], acc[k]);
    ssum += w;
  }

  // quad combine (DPP, full rate)
  #pragma unroll
  for (int k = 0; k < 16; ++k) {
    acc[k] += __shfl_xor(acc[k], 1, 64);
    acc[k] += __shfl_xor(acc[k], 2, 64);
  }
  ssum += __shfl_xor(ssum, 1, 64);
  ssum += __shfl_xor(ssum, 2, 64);
  const float inv = 1.0f / ssum;
  float o[16];
  #pragma unroll
  for (int k = 0; k < 16; ++k) o[k] = acc[k] * inv;

  if (!FINAL) {
    if (es == 0) {
      float ss = 0.f;
      #pragma unroll
      for (int k = 0; k < 16; ++k) ss = fmaf(o[k], o[k], ss);
      rno[n] = 1.0f / fmaxf(sqrtf(ss), EPSF);
      uint4 w0, w1;
      w0.x = (unsigned)f2bf(o[0])  | ((unsigned)f2bf(o[1])  << 16);
      w0.y = (unsigned)f2bf(o[2])  | ((unsigned)f2bf(o[3])  << 16);
      w0.z = (unsigned)f2bf(o[4])  | ((unsigned)f2bf(o[5])  << 16);
      w0.w = (unsigned)f2bf(o[6])  | ((unsigned)f2bf(o[7])  << 16);
      w1.x = (unsigned)f2bf(o[8])  | ((unsigned)f2bf(o[9])  << 16);
      w1.y = (unsigned)f2bf(o[10]) | ((unsigned)f2bf(o[11]) << 16);
      w1.z = (unsigned)f2bf(o[12]) | ((unsigned)f2bf(o[13]) << 16);
      w1.w = (unsigned)f2bf(o[14]) | ((unsigned)f2bf(o[15]) << 16);
      *(uint4*)(ho + (size_t)n * NH)     = w0;
      *(uint4*)(ho + (size_t)n * NH + 8) = w1;
    }
  } else {
    float lg[4];
    #pragma unroll
    for (int jj = 0; jj < 4; ++jj) {
      const int j = es * 4 + jj;
      float a = b2[j];
      #pragma unroll
      for (int k = 0; k < 16; ++k) a = fmaf(o[k], W2[k * NC + j], a);
      lg[jj] = a;
    }
    float m = fmaxf(fmaxf(lg[0], lg[1]), fmaxf(lg[2], lg[3]));
    m = fmaxf(m, __shfl_xor(m, 1, 64));
    m = fmaxf(m, __shfl_xor(m, 2, 64));
    float se = __expf(lg[0] - m) + __expf(lg[1] - m) +
               __expf(lg[2] - m) + __expf(lg[3] - m);
    se += __shfl_xor(se, 1, 64);
    se += __shfl_xor(se, 2, 64);
    const float ls = m + __logf(se);
    *(float4*)(out + (size_t)n * NC + es * 4) =
        make_float4(lg[0] - ls, lg[1] - ls, lg[2] - ls, lg[3] - ls);
  }
}

extern "C" void kernel_launch(void* const* d_in, const int* in_sizes, int n_in,
                              void* d_out, int out_size, void* d_ws, size_t ws_size,
                              hipStream_t stream) {
  const float* x     = (const float*)d_in[0];
  const int*   ei    = (const int*)d_in[1];
  const float* W1    = (const float*)d_in[2];
  const float* b1    = (const float*)d_in[3];
  const float* W2    = (const float*)d_in[4];
  const float* b2    = (const float*)d_in[5];
  const float* beta2 = (const float*)d_in[6];
  float* out = (float*)d_out;

  char* ws = (char*)d_ws;
  size_t o = 0;
  auto alloc = [&](size_t bytes) -> void* {
    o = (o + 255) & ~(size_t)255;
    void* p = ws + o;
    o += bytes;
    return p;
  };
  u16*      h1    = (u16*)alloc((size_t)NN * NH * 2);
  u16*      h2    = (u16*)alloc((size_t)NN * NH * 2);
  float*    rn1   = (float*)alloc((size_t)NN * 4);
  float*    rn2   = (float*)alloc((size_t)NN * 4);
  int*      bcnt  = (int*)alloc((size_t)NBUK * 4);
  int*      bbase = (int*)alloc((size_t)NBUK * 4);
  int*      bcur  = (int*)alloc((size_t)NBUK * 4);
  int*      nbase = (int*)alloc((size_t)NN * 4);
  int*      ndeg  = (int*)alloc((size_t)NN * 4);
  unsigned* csrg  = (unsigned*)alloc((size_t)NBUK * SCAP * 4);
  unsigned* stg   = (unsigned*)alloc(((size_t)NE + (size_t)NBUK * (BSLACK + 16)) * 4);

  const int* esrc = ei;
  const int* edst = ei + NE;
  const int nfeat = (NN + 63) / 64;  // 1563 (also = prop grid: 64 quads/block)

  k_feat<<<nfeat, 256, 0, stream>>>(x, W1, b1, h1, rn1, bcnt);
  k_bcount<<<512, 256, 0, stream>>>(edst, bcnt);
  k_bscan<<<1, 512, 0, stream>>>(bcnt, bbase, bcur);
  k_bin<<<BIN_BLOCKS, BIN_T, 0, stream>>>(esrc, edst, bcur, stg);
  k_sort<<<NBUK, 1024, 0, stream>>>(stg, bbase, bcur, csrg, nbase, ndeg);
  k_prop<false><<<nfeat, 256, 0, stream>>>(h1, rn1, csrg, nbase, ndeg, nullptr,
                                           h2, rn2, nullptr, nullptr, nullptr);
  k_prop<true><<<nfeat, 256, 0, stream>>>(h2, rn2, csrg, nbase, ndeg, beta2,
                                          nullptr, nullptr, W2, b2, out);
}

// Round 9
// 225.108 us; speedup vs baseline: 1.1280x; 1.1280x over previous
//
#include <hip/hip_runtime.h>
#include <hip/hip_bf16.h>

#define NN 100000
#define NE 3200000
#define NF 512
#define NH 16
#define NC 16
#define EPSF 1e-12f

// Bucket = 256 consecutive dst nodes. Fixed staging region per bucket:
// cap 9216 = mean 8192 + 11 sigma (counts fixed by input; guarded anyway).
#define BNODES 256
#define NBUK 391
#define BIN_BLOCKS 128
#define BIN_T 1024
#define BCAP 32
#define SCAP 9216
#define RECW 16   // node record = 16 u32 = 64B: [0..7]=h bf16 pairs, [8]=rn f32

typedef unsigned short u16;
typedef unsigned int u32;

__device__ __forceinline__ u16 f2bf(float f) {
  u32 u = __float_as_uint(f);
  u += 0x7fffu + ((u >> 16) & 1u);   // round-to-nearest-even
  return (u16)(u >> 16);
}
// unpack 8 bf16 (one uint4 of pairs, low half first) to f32
__device__ __forceinline__ void unpack8(uint4 q, float* f) {
  f[0] = __uint_as_float(q.x << 16); f[1] = __uint_as_float(q.x & 0xffff0000u);
  f[2] = __uint_as_float(q.y << 16); f[3] = __uint_as_float(q.y & 0xffff0000u);
  f[4] = __uint_as_float(q.z << 16); f[5] = __uint_as_float(q.z & 0xffff0000u);
  f[6] = __uint_as_float(q.w << 16); f[7] = __uint_as_float(q.w & 0xffff0000u);
}

// ---------------- k_feat: rec1 = {relu(x@W1+b1) bf16, rnorm}; init bcur ------
// Block = 4 waves = 64 rows; wave q owns K-quarter, W1 via wave-uniform s_load.
__global__ __launch_bounds__(256) void k_feat(const float* __restrict__ x,
    const float* __restrict__ W1, const float* __restrict__ b1,
    u32* __restrict__ rec, int* __restrict__ bcur) {
  const int tid = threadIdx.x;
  for (int g = blockIdx.x * 256 + tid; g < NBUK; g += gridDim.x * 256)
    bcur[g] = g * SCAP;                 // fixed-region cursor init

  __shared__ float part[4][64][20];

  const int lane = tid & 63;
  const int q = __builtin_amdgcn_readfirstlane(tid >> 6);
  const int base = blockIdx.x * 64;
  int row = base + lane;
  if (row >= NN) row = NN - 1;

  const float* wq = W1 + q * 128 * NH;  // wave-uniform -> s_load via K$
  const float4* xp = (const float4*)(x + (size_t)row * NF + q * 128);

  float acc[16];
  #pragma unroll
  for (int j = 0; j < 16; ++j) acc[j] = 0.f;

  #pragma unroll 2
  for (int kk = 0; kk < 32; ++kk) {
    const float4 xv = xp[kk];
    #pragma unroll
    for (int dk = 0; dk < 4; ++dk) {
      const float* wrow = wq + (kk * 4 + dk) * NH;
      const float xs = (dk == 0) ? xv.x : (dk == 1) ? xv.y : (dk == 2) ? xv.z : xv.w;
      #pragma unroll
      for (int j = 0; j < 16; ++j)
        acc[j] = fmaf(xs, wrow[j], acc[j]);
    }
  }

  #pragma unroll
  for (int j4 = 0; j4 < 4; ++j4)
    *(float4*)&part[q][lane][j4 * 4] =
        make_float4(acc[j4 * 4], acc[j4 * 4 + 1], acc[j4 * 4 + 2], acc[j4 * 4 + 3]);
  __syncthreads();

  const int r2 = tid >> 2;
  const int t4 = tid & 3;
  const int jg = t4 * 4;
  const int orow = base + r2;
  float o[4];
  #pragma unroll
  for (int jj = 0; jj < 4; ++jj) {
    const int j = jg + jj;
    float s = part[0][r2][j] + part[1][r2][j] + part[2][r2][j] + part[3][r2][j];
    o[jj] = fmaxf(s + b1[j], 0.f);
  }
  float ss = o[0] * o[0] + o[1] * o[1] + o[2] * o[2] + o[3] * o[3];
  ss += __shfl_xor(ss, 1, 64);
  ss += __shfl_xor(ss, 2, 64);
  const float rv = 1.0f / fmaxf(sqrtf(ss), EPSF);
  if (orow < NN) {
    u32* rp = rec + (size_t)orow * RECW;
    uint2 hv;
    hv.x = (u32)f2bf(o[0]) | ((u32)f2bf(o[1]) << 16);
    hv.y = (u32)f2bf(o[2]) | ((u32)f2bf(o[3]) << 16);
    *(uint2*)(rp + t4 * 2) = hv;
    if (t4 == 0) ((float*)rp)[8] = rv;
  }
}

// ---------------- k_bin: LDS line-assembled bucket binning -------------------
// Entry = (src<<8)|dst_local. Full 64B-line flushes during batches; partial
// (exact-count) tail flush at end -> no sentinels anywhere.
__global__ __launch_bounds__(BIN_T) void k_bin(const int* __restrict__ srcs,
    const int* __restrict__ dsts, int* __restrict__ bcur, u32* __restrict__ stg) {
  __shared__ u32 buf[NBUK][BCAP];
  __shared__ int cnt[NBUK];
  const int tid = threadIdx.x;
  for (int i = tid; i < NBUK; i += BIN_T) cnt[i] = 0;
  __syncthreads();
  const int perblk = (NE + BIN_BLOCKS - 1) / BIN_BLOCKS;   // 25000
  const int e0 = blockIdx.x * perblk;
  const int e1 = (e0 + perblk < NE) ? e0 + perblk : NE;
  for (int base = e0; base < e1; base += BIN_T) {
    const int e = base + tid;
    if (e < e1) {
      const int d = dsts[e];
      const u32 pv = ((u32)srcs[e] << 8) | (u32)(d & (BNODES - 1));
      const int b = d >> 8;
      const int slot = atomicAdd(&cnt[b], 1);
      if (slot < BCAP) {
        buf[b][slot] = pv;
      } else {                          // ~never: single-entry spill
        const int g = atomicAdd(&bcur[b], 1);
        if (g < (b + 1) * SCAP) stg[g] = pv;
        atomicSub(&cnt[b], 1);
      }
    }
    __syncthreads();
    for (int b = tid; b < NBUK; b += BIN_T) {   // flush full 64B lines
      int c = cnt[b];
      while (c >= 16) {
        const int g = atomicAdd(&bcur[b], 16);
        if (g + 16 <= (b + 1) * SCAP) {
          #pragma unroll
          for (int t = 0; t < 16; t += 4)
            *(uint4*)&stg[g + t] = make_uint4(buf[b][c - 16 + t], buf[b][c - 15 + t],
                                              buf[b][c - 14 + t], buf[b][c - 13 + t]);
        }
        c -= 16;
      }
      cnt[b] = c;
    }
    __syncthreads();
  }
  for (int b = tid; b < NBUK; b += BIN_T) {      // exact-count partial tail
    const int c = cnt[b];
    if (c > 0) {
      const int g = atomicAdd(&bcur[b], c);
      if (g + c <= (b + 1) * SCAP)
        for (int t = 0; t < c; ++t) stg[g + t] = buf[b][t];
    }
  }
}

// ---------------- k_sp1: bucket counting-sort + prop1 (beta=1) fused ---------
// Sort into LDS srt (+1 pad slot/node), flush sorted list to csrg for prop2,
// then quad-per-node register compute reading srt from LDS (zero L2 for edges).
__global__ __launch_bounds__(1024) void k_sp1(const u32* __restrict__ rec1,
    const u32* __restrict__ stg, const int* __restrict__ bcur,
    u32* __restrict__ rec2, u32* __restrict__ csrg,
    int* __restrict__ nbase, int* __restrict__ ndeg) {
  __shared__ u32 srt[SCAP];             // 36 KB
  __shared__ int sm[BNODES];
  __shared__ int lbase[BNODES];
  __shared__ int lcur[BNODES];

  const int tid = threadIdx.x;
  const int b = blockIdx.x;
  const int n0 = b * BNODES;
  const int nloc = (NN - n0 < BNODES) ? NN - n0 : BNODES;
  const int s0 = b * SCAP;
  int ecnt = bcur[b] - s0;
  if (ecnt > SCAP) ecnt = SCAP;

  if (tid < BNODES) sm[tid] = 0;
  __syncthreads();

  for (int i = tid; i < ecnt; i += 1024)              // per-node count
    atomicAdd(&sm[stg[s0 + i] & (BNODES - 1)], 1);
  __syncthreads();

  int myc = 0;                                         // scan of (cnt+1)
  if (tid < BNODES) { myc = sm[tid]; sm[tid] = myc + 1; }
  __syncthreads();
  for (int s = 1; s < BNODES; s <<= 1) {
    int t = (tid < BNODES && tid >= s) ? sm[tid - s] : 0;
    __syncthreads();
    if (tid < BNODES) sm[tid] += t;
    __syncthreads();
  }
  if (tid < BNODES) {
    const int ex = sm[tid] - (myc + 1);
    lbase[tid] = ex;
    lcur[tid] = ex;
  }
  __syncthreads();

  for (int i = tid; i < ecnt; i += 1024) {            // scatter-sort into LDS
    const u32 v = stg[s0 + i];
    const int slot = atomicAdd(&lcur[v & (BNODES - 1)], 1);
    if (slot < SCAP) srt[slot] = v >> 8;
  }
  __syncthreads();

  int tot = sm[BNODES - 1];                            // flush sorted list
  if (tot > SCAP) tot = SCAP;
  for (int i = tid; i < tot; i += 1024) csrg[s0 + i] = srt[i];
  if (tid < nloc) {
    nbase[n0 + tid] = s0 + lbase[tid];
    ndeg[n0 + tid] = lcur[tid] - lbase[tid];
  }

  // ---- prop1 compute: 4 threads/node, edges from LDS srt ----
  const int nl = tid >> 2;
  const int es = tid & 3;
  if (nl < nloc) {
    const int n = n0 + nl;
    const u32* rp = rec1 + (size_t)n * RECW;
    const uint4 d0 = *(const uint4*)rp;
    const uint4 d1 = *(const uint4*)(rp + 4);
    float hd[16];
    unpack8(d0, hd); unpack8(d1, hd + 8);
    const float rv = ((const float*)rp)[8];
    const int off = lbase[nl];
    const int deg = lcur[nl] - lbase[nl];

    float acc[16];
    #pragma unroll
    for (int k = 0; k < 16; ++k) acc[k] = 0.f;
    float ssum = 0.f;

    for (int i = es; i < deg + 1; i += 4) {           // +1 virtual self-loop
      float hs[16], rns;
      if (i < deg) {
        const int src = (int)srt[off + i];
        const u32* sp = rec1 + (size_t)src * RECW;
        const uint4 q0 = *(const uint4*)sp;
        const uint4 q1 = *(const uint4*)(sp + 4);
        unpack8(q0, hs); unpack8(q1, hs + 8);
        rns = ((const float*)sp)[8];
      } else {
        #pragma unroll
        for (int k = 0; k < 16; ++k) hs[k] = hd[k];
        rns = rv;
      }
      float p0 = 0.f, p1 = 0.f, p2 = 0.f, p3 = 0.f;
      #pragma unroll
      for (int k = 0; k < 4; ++k) {
        p0 = fmaf(hs[k],      hd[k],      p0);
        p1 = fmaf(hs[k + 4],  hd[k + 4],  p1);
        p2 = fmaf(hs[k + 8],  hd[k + 8],  p2);
        p3 = fmaf(hs[k + 12], hd[k + 12], p3);
      }
      const float p = (p0 + p1) + (p2 + p3);
      const float w = __expf(rv * rns * p);           // beta = 1
      #pragma unroll
      for (int k = 0; k < 16; ++k) acc[k] = fmaf(w, hs[k], acc[k]);
      ssum += w;
    }

    #pragma unroll
    for (int k = 0; k < 16; ++k) {
      acc[k] += __shfl_xor(acc[k], 1, 64);
      acc[k] += __shfl_xor(acc[k], 2, 64);
    }
    ssum += __shfl_xor(ssum, 1, 64);
    ssum += __shfl_xor(ssum, 2, 64);

    if (es == 0) {
      const float inv = 1.0f / ssum;
      float o[16];
      #pragma unroll
      for (int k = 0; k < 16; ++k) o[k] = acc[k] * inv;
      float ss2 = 0.f;
      #pragma unroll
      for (int k = 0; k < 16; ++k) ss2 = fmaf(o[k], o[k], ss2);
      const float rno = 1.0f / fmaxf(sqrtf(ss2), EPSF);
      u32* op = rec2 + (size_t)n * RECW;
      uint4 w0, w1;
      w0.x = (u32)f2bf(o[0])  | ((u32)f2bf(o[1])  << 16);
      w0.y = (u32)f2bf(o[2])  | ((u32)f2bf(o[3])  << 16);
      w0.z = (u32)f2bf(o[4])  | ((u32)f2bf(o[5])  << 16);
      w0.w = (u32)f2bf(o[6])  | ((u32)f2bf(o[7])  << 16);
      w1.x = (u32)f2bf(o[8])  | ((u32)f2bf(o[9])  << 16);
      w1.y = (u32)f2bf(o[10]) | ((u32)f2bf(o[11]) << 16);
      w1.z = (u32)f2bf(o[12]) | ((u32)f2bf(o[13]) << 16);
      w1.w = (u32)f2bf(o[14]) | ((u32)f2bf(o[15]) << 16);
      *(uint4*)op = w0;
      *(uint4*)(op + 4) = w1;
      ((float*)op)[8] = rno;
    }
  }
}

// ---------------- k_sp2: prop2 + W2 + log_softmax, pure gather-compute -------
__global__ __launch_bounds__(256) void k_sp2(const u32* __restrict__ rec,
    const u32* __restrict__ csrg, const int* __restrict__ nbase,
    const int* __restrict__ ndeg, const float* __restrict__ betap,
    const float* __restrict__ W2, const float* __restrict__ b2,
    float* __restrict__ out) {
  const int t = blockIdx.x * 256 + threadIdx.x;
  const int es = t & 3;
  const int n = t >> 2;
  if (n >= NN) return;
  const float beta = betap[0];

  const u32* rp = rec + (size_t)n * RECW;
  const uint4 d0 = *(const uint4*)rp;
  const uint4 d1 = *(const uint4*)(rp + 4);
  float hd[16];
  unpack8(d0, hd); unpack8(d1, hd + 8);
  const float rv = ((const float*)rp)[8];
  const float brd = beta * rv;
  const int off = nbase[n];
  const int deg = ndeg[n];

  float acc[16];
  #pragma unroll
  for (int k = 0; k < 16; ++k) acc[k] = 0.f;
  float ssum = 0.f;

  for (int i = es; i < deg + 1; i += 4) {             // +1 virtual self-loop
    float hs[16], rns;
    if (i < deg) {
      const int src = (int)csrg[off + i];
      const u32* sp = rec + (size_t)src * RECW;
      const uint4 q0 = *(const uint4*)sp;
      const uint4 q1 = *(const uint4*)(sp + 4);
      unpack8(q0, hs); unpack8(q1, hs + 8);
      rns = ((const float*)sp)[8];
    } else {
      #pragma unroll
      for (int k = 0; k < 16; ++k) hs[k] = hd[k];
      rns = rv;
    }
    float p0 = 0.f, p1 = 0.f, p2 = 0.f, p3 = 0.f;
    #pragma unroll
    for (int k = 0; k < 4; ++k) {
      p0 = fmaf(hs[k],      hd[k],      p0);
      p1 = fmaf(hs[k + 4],  hd[k + 4],  p1);
      p2 = fmaf(hs[k + 8],  hd[k + 8],  p2);
      p3 = fmaf(hs[k + 12], hd[k + 12], p3);
    }
    const float p = (p0 + p1) + (p2 + p3);
    const float w = __expf(brd * rns * p);
    #pragma unroll
    for (int k = 0; k < 16; ++k) acc[k] = fmaf(w, hs[k], acc[k]);
    ssum += w;
  }

  #pragma unroll
  for (int k = 0; k < 16; ++k) {
    acc[k] += __shfl_xor(acc[k], 1, 64);
    acc[k] += __shfl_xor(acc[k], 2, 64);
  }
  ssum += __shfl_xor(ssum, 1, 64);
  ssum += __shfl_xor(ssum, 2, 64);
  const float inv = 1.0f / ssum;
  float o[16];
  #pragma unroll
  for (int k = 0; k < 16; ++k) o[k] = acc[k] * inv;

  float lg[4];
  #pragma unroll
  for (int jj = 0; jj < 4; ++jj) {
    const int j = es * 4 + jj;
    float a = b2[j];
    #pragma unroll
    for (int k = 0; k < 16; ++k) a = fmaf(o[k], W2[k * NC + j], a);
    lg[jj] = a;
  }
  float m = fmaxf(fmaxf(lg[0], lg[1]), fmaxf(lg[2], lg[3]));
  m = fmaxf(m, __shfl_xor(m, 1, 64));
  m = fmaxf(m, __shfl_xor(m, 2, 64));
  float se = __expf(lg[0] - m) + __expf(lg[1] - m) +
             __expf(lg[2] - m) + __expf(lg[3] - m);
  se += __shfl_xor(se, 1, 64);
  se += __shfl_xor(se, 2, 64);
  const float ls = m + __logf(se);
  *(float4*)(out + (size_t)n * NC + es * 4) =
      make_float4(lg[0] - ls, lg[1] - ls, lg[2] - ls, lg[3] - ls);
}

extern "C" void kernel_launch(void* const* d_in, const int* in_sizes, int n_in,
                              void* d_out, int out_size, void* d_ws, size_t ws_size,
                              hipStream_t stream) {
  const float* x     = (const float*)d_in[0];
  const int*   ei    = (const int*)d_in[1];
  const float* W1    = (const float*)d_in[2];
  const float* b1    = (const float*)d_in[3];
  const float* W2    = (const float*)d_in[4];
  const float* b2    = (const float*)d_in[5];
  const float* beta2 = (const float*)d_in[6];
  float* out = (float*)d_out;

  char* ws = (char*)d_ws;
  size_t o = 0;
  auto alloc = [&](size_t bytes) -> void* {
    o = (o + 255) & ~(size_t)255;
    void* p = ws + o;
    o += bytes;
    return p;
  };
  u32* rec1  = (u32*)alloc((size_t)NN * RECW * 4);
  u32* rec2  = (u32*)alloc((size_t)NN * RECW * 4);
  u32* stg   = (u32*)alloc((size_t)NBUK * SCAP * 4);
  u32* csrg  = (u32*)alloc((size_t)NBUK * SCAP * 4);
  int* nbase = (int*)alloc((size_t)NN * 4);
  int* ndeg  = (int*)alloc((size_t)NN * 4);
  int* bcur  = (int*)alloc((size_t)NBUK * 4);

  const int* esrc = ei;
  const int* edst = ei + NE;
  const int nfeat = (NN + 63) / 64;  // 1563

  k_feat<<<nfeat, 256, 0, stream>>>(x, W1, b1, rec1, bcur);
  k_bin<<<BIN_BLOCKS, BIN_T, 0, stream>>>(esrc, edst, bcur, stg);
  k_sp1<<<NBUK, 1024, 0, stream>>>(rec1, stg, bcur, rec2, csrg, nbase, ndeg);
  k_sp2<<<nfeat, 256, 0, stream>>>(rec2, csrg, nbase, ndeg, beta2, W2, b2, out);
}